// Round 6
// baseline (500.022 us; speedup 1.0000x reference)
//
#include <hip/hip_runtime.h>

typedef unsigned short u16;
typedef __bf16  bf16x8 __attribute__((ext_vector_type(8)));
typedef float   f32x4  __attribute__((ext_vector_type(4)));
typedef float   f32x16 __attribute__((ext_vector_type(16)));
typedef u16     u16x8  __attribute__((ext_vector_type(8)));
typedef u16     u16x4  __attribute__((ext_vector_type(4)));

#define QSCALE 0.12751744545f   // log2(e)/sqrt(128)

// ---------------------------------------------------------------------------
// helpers
// ---------------------------------------------------------------------------
__device__ __forceinline__ u16 f2b(float f) {               // f32 -> bf16 (RNE)
    unsigned u = __float_as_uint(f);
    unsigned r = u + 0x7FFFu + ((u >> 16) & 1u);
    return (u16)(r >> 16);
}
__device__ __forceinline__ float b2f(u16 b) {
    return __uint_as_float(((unsigned)b) << 16);
}
__device__ __forceinline__ void async16(const u16* g, u16* l) {
    // lane L's 16B land at (wave-uniform l) + L*16
    __builtin_amdgcn_global_load_lds(
        (__attribute__((address_space(1))) void*)(u16*)g,
        (__attribute__((address_space(3))) void*)l, 16, 0, 0);
}

// ---------------------------------------------------------------------------
// fp32 -> bf16 convert (float4 per thread)
// ---------------------------------------------------------------------------
__global__ void cvt_f32_bf16(const float* __restrict__ in, u16* __restrict__ out, int n4) {
    int i = blockIdx.x * blockDim.x + threadIdx.x;
    if (i >= n4) return;
    float4 f = ((const float4*)in)[i];
    u16x4 o;
    o[0] = f2b(f.x); o[1] = f2b(f.y); o[2] = f2b(f.z); o[3] = f2b(f.w);
    *(u16x4*)(out + (size_t)i * 4) = o;
}

// wqkv convert with q-row pre-scale folded in (rows with (row%384)<128 are q)
__global__ void cvt_wqkv(const float* __restrict__ in, u16* __restrict__ out, int n4) {
    int i = blockIdx.x * blockDim.x + threadIdx.x;
    if (i >= n4) return;
    int row = i >> 9;                       // 512 float4 per 2048-elem row
    float s = ((row % 384) < 128) ? QSCALE : 1.0f;
    float4 f = ((const float4*)in)[i];
    u16x4 o;
    o[0] = f2b(f.x * s); o[1] = f2b(f.y * s); o[2] = f2b(f.z * s); o[3] = f2b(f.w * s);
    *(u16x4*)(out + (size_t)i * 4) = o;
}

// ---------------------------------------------------------------------------
// bf16 NT GEMM: C = A[M,K] * B[N,K]^T + bias   (128x128 tile, BK=64, 2 panels)
// mode 0 (QKV fused): blockIdx.x = nh*3+part; writes qb/kb [bn][pos][hd]
//        directly (scrambled coords), v transposed through LDS to vb[bn][hd][pos]
// mode 1: store f32 with row remap orow = (row&1)*2048 + (row>>1)  (final out)
// ---------------------------------------------------------------------------
__global__ __launch_bounds__(256) void gemm_bt(
    const u16* __restrict__ A, const u16* __restrict__ B,
    const float* __restrict__ bias, void* __restrict__ C,
    u16* __restrict__ qb, u16* __restrict__ kb, u16* __restrict__ vb,
    int M, int N, int K, int mode)
{
    __shared__ u16 smem[16384];          // 32 KB: As | Bs, reused as v-transpose buf
    u16* As = smem;                      // [p][row][32k] : p*4096 + row*32 + kk
    u16* Bs = smem + 8192;

    int tid = threadIdx.x, wave = tid >> 6, lane = tid & 63;
    int lg = lane >> 4, lm = lane & 15;
    int wm = (wave & 1) * 64, wn = (wave >> 1) * 64;

    const u16* Ab = A + (size_t)(blockIdx.y * 128) * K;
    const u16* Bb = B + (size_t)(blockIdx.x * 128) * K;

    f32x4 acc[4][4];
    for (int i = 0; i < 4; i++)
        for (int j = 0; j < 4; j++)
            acc[i][j] = (f32x4){0.f, 0.f, 0.f, 0.f};

    int srow = (lane >> 2), skq = (lane & 3) * 8;   // lane -> row/k within 1KB chunk

    for (int k0 = 0; k0 < K; k0 += 64) {
        __syncthreads();
        for (int cc = wave; cc < 16; cc += 4) {
            int p = cc >> 3, c = cc & 7;
            int row = c * 16 + srow;
            size_t off = (size_t)row * K + k0 + p * 32 + skq;
            async16(Ab + off, &As[p * 4096 + c * 512]);
            async16(Bb + off, &Bs[p * 4096 + c * 512]);
        }
        __syncthreads();   // compiler drains vmcnt before barrier

        for (int p = 0; p < 2; p++) {
            bf16x8 af[4], bf[4];
            for (int i = 0; i < 4; i++) af[i] = *(const bf16x8*)&As[p * 4096 + (wm + i * 16 + lm) * 32 + lg * 8];
            for (int j = 0; j < 4; j++) bf[j] = *(const bf16x8*)&Bs[p * 4096 + (wn + j * 16 + lm) * 32 + lg * 8];
            for (int i = 0; i < 4; i++)
                for (int j = 0; j < 4; j++)
                    acc[i][j] = __builtin_amdgcn_mfma_f32_16x16x32_bf16(af[i], bf[j], acc[i][j], 0, 0, 0);
        }
    }

    if (mode == 1) {   // final output: f32, row remap
        for (int j = 0; j < 4; j++) {
            int col = blockIdx.x * 128 + wn + j * 16 + lm;
            float bv = bias[col];
            for (int i = 0; i < 4; i++) {
                int row0 = blockIdx.y * 128 + wm + i * 16 + lg * 4;
                for (int r = 0; r < 4; r++) {
                    int row = row0 + r;
                    int orow = ((row & 1) << 11) + (row >> 1);
                    ((float*)C)[(size_t)orow * N + col] = acc[i][j][r] + bv;
                }
            }
        }
        return;
    }

    // ---- mode 0: fused QKV scatter epilogue ----
    int ct = blockIdx.x;
    int nh = ct / 3, part = ct - nh * 3;
    float bscale = (part == 0) ? QSCALE : 1.0f;
    int rbase = blockIdx.y * 128;                 // global row base (= b*2048 + s0)
    int b = rbase >> 11;
    int s0 = rbase & 2047;

    if (part < 2) {   // q or k -> [bn][pos][hd], scalar u16 stores (32B runs)
        u16* dst0 = part ? kb : qb;
        for (int j = 0; j < 4; j++) {
            int hd = wn + j * 16 + lm;
            float bv = bias[ct * 128 + hd] * bscale;
            for (int i = 0; i < 4; i++) {
                for (int r = 0; r < 4; r++) {
                    int rl = wm + i * 16 + lg * 4 + r;       // local row 0..127
                    int s = s0 + rl;
                    int bn = (s & 1) * 16 + nh;
                    int pos = (b << 10) + (s >> 1);
                    dst0[((size_t)(bn * 2048 + pos)) * 128 + hd] = f2b(acc[i][j][r] + bv);
                }
            }
        }
    } else {          // v -> transpose via LDS -> vb[bn][hd][pos] (128B runs)
        u16 (*arr)[64][128] = (u16(*)[64][128])smem;   // [par][pos_local][hd]
        __syncthreads();   // all waves done reading As/Bs
        for (int j = 0; j < 4; j++) {
            int hd = wn + j * 16 + lm;
            float bv = bias[ct * 128 + hd];
            for (int i = 0; i < 4; i++) {
                for (int r = 0; r < 4; r++) {
                    int rl = wm + i * 16 + lg * 4 + r;
                    arr[rl & 1][rl >> 1][hd] = f2b(acc[i][j][r] + bv);
                }
            }
        }
        __syncthreads();
        int hd = tid & 127, par = tid >> 7;
        int bn = par * 16 + nh;
        int pos0 = (b << 10) + (s0 >> 1);
        u16* dst = vb + ((size_t)(bn * 128 + hd)) * 2048 + pos0;
        for (int c = 0; c < 8; c++) {
            u16x8 w;
            for (int e = 0; e < 8; e++) w[e] = arr[par][c * 8 + e][hd];
            *(u16x8*)(dst + c * 8) = w;
        }
    }
}

// ---------------------------------------------------------------------------
// flash attention, scrambled (bn,pos) space — 32x32x16 MFMA edition.
// Q-tile 128 rows/block (32/wave), K-tiles of 64, double-buffered K/V LDS
// (one barrier per iter, staging overlaps MFMA). No-max softmax (shift 8,
// log2e in q), row sums via ones-MFMA. Diagonal pairing: block p does
// qt = p and 15-p -> uniform 36 iters. 256 blocks, 1 per CU.
// C/D 32x32 layout: col = lane&31, row = (reg&3) + 8*(reg>>2) + 4*(lane>>5).
// A/B layouts: A[m=lane&31][k=(lane>>5)*8+j], B[k=(lane>>5)*8+j][n=lane&31].
// writes ctx bf16 [pos*2 + bn>>4][(bn&15)*128 + hd]
// ---------------------------------------------------------------------------
__global__ __launch_bounds__(256, 1) void attn(
    const u16* __restrict__ qb, const u16* __restrict__ kb,
    const u16* __restrict__ vb, const float* __restrict__ alibi,
    u16* __restrict__ ctx)
{
    __shared__ u16 Ks[2][64 * 140];     // K tile [kpos][hd], stride 140 (odd dwords)
    __shared__ u16 Vt[2][128 * 90];     // V^T tile [hd][kpos], stride 90
    __shared__ u16 Ps[4][32 * 74];      // per-wave P [q32][k64], stride 74

    int bn = blockIdx.y;
    int tid = threadIdx.x, wave = tid >> 6, lane = tid & 63;
    int ln = lane & 31, lh = lane >> 5;

    const float* al = alibi + (bn & 15) * 2048;

    int krow = tid >> 2, kq = (tid & 3) * 32;
    int vhd  = tid >> 1, vh2 = (tid & 1) * 32;
    const u16* ksrc0 = kb + (size_t)(bn * 2048 + krow) * 128 + kq;
    const u16* vsrc0 = vb + (size_t)(bn * 128 + vhd) * 2048 + vh2;

    u16* ps = &Ps[wave][0];
    bf16x8 ones;
    {
        u16x8 t;
        for (int j = 0; j < 8; j++) t[j] = 0x3F80;   // bf16 1.0
        ones = *(bf16x8*)&t;
    }

    for (int pass = 0; pass < 2; pass++) {
        int qt = pass ? (15 - blockIdx.x) : blockIdx.x;
        int q0w = qt * 128 + wave * 32;     // this wave's first q row
        int ktmax = 2 * qt + 1;

        // Q fragments: 8 k-steps of 16 along hd
        bf16x8 qf[8];
        {
            const u16* qp = qb + ((size_t)bn * 2048 + q0w + ln) * 128 + lh * 8;
            for (int ks = 0; ks < 8; ks++) qf[ks] = *(const bf16x8*)(qp + ks * 16);
        }

        f32x16 o[4], sums;
        for (int e = 0; e < 16; e++) { sums[e] = 0.f; o[0][e] = 0.f; o[1][e] = 0.f; o[2][e] = 0.f; o[3][e] = 0.f; }

        // stage tile 0 into buffer 0
        u16x8 kreg[4], vreg[4];
        for (int i = 0; i < 4; i++) kreg[i] = *(const u16x8*)(ksrc0 + i * 8);
        for (int i = 0; i < 4; i++) vreg[i] = *(const u16x8*)(vsrc0 + i * 8);
        {
            u16* d1 = &Ks[0][krow * 140 + kq];
            for (int i = 0; i < 4; i++) *(u16x8*)(d1 + i * 8) = kreg[i];
            u16* d2 = &Vt[0][vhd * 90 + vh2];
            for (int i = 0; i < 4; i++) *(u16x8*)(d2 + i * 8) = vreg[i];
        }
        __syncthreads();

        for (int kt = 0; kt <= ktmax; kt++) {
            int cur = kt & 1;
            int k0 = kt * 64;

            // issue global prefetch of next tile (lands during MFMA below)
            if (kt < ktmax) {
                const u16* s1 = ksrc0 + (size_t)(kt + 1) * 64 * 128;
                const u16* s2 = vsrc0 + (kt + 1) * 64;
                for (int i = 0; i < 4; i++) kreg[i] = *(const u16x8*)(s1 + i * 8);
                for (int i = 0; i < 4; i++) vreg[i] = *(const u16x8*)(s2 + i * 8);
            }

            // S = Q K^T : two 32x32 col-tiles, 8 k-steps each
            bool domask = (k0 + 63 > q0w);
            for (int ct = 0; ct < 2; ct++) {
                const u16* kr = &Ks[cur][(ct * 32 + ln) * 140 + lh * 8];
                f32x16 a;
                for (int e = 0; e < 16; e++) a[e] = 0.f;
                for (int ks = 0; ks < 8; ks++)
                    a = __builtin_amdgcn_mfma_f32_32x32x16_bf16(qf[ks], *(const bf16x8*)(kr + ks * 16), a, 0, 0, 0);

                // softmax + P store (per-wave LDS region, no block sync)
                int kg = k0 + ct * 32 + ln;
                float av = (al[kg] - 8.0f) * 1.4426950408889634f;
                for (int reg = 0; reg < 16; reg++) {
                    int row = (reg & 3) + 8 * (reg >> 2) + 4 * lh;
                    float v = a[reg] + av;
                    if (domask && kg > q0w + row) v = -3e38f;
                    ps[row * 74 + ct * 32 + ln] = f2b(__builtin_amdgcn_exp2f(v));
                }
            }

            // O += P V ; sums += P * ones   (4 k-steps of 16)
            for (int ks = 0; ks < 4; ks++) {
                bf16x8 pa = *(const bf16x8*)&ps[ln * 74 + ks * 16 + lh * 8];
                sums = __builtin_amdgcn_mfma_f32_32x32x16_bf16(pa, ones, sums, 0, 0, 0);
                for (int ht = 0; ht < 4; ht++) {
                    bf16x8 vf = *(const bf16x8*)&Vt[cur][(ht * 32 + ln) * 90 + ks * 16 + lh * 8];
                    o[ht] = __builtin_amdgcn_mfma_f32_32x32x16_bf16(pa, vf, o[ht], 0, 0, 0);
                }
            }

            // write next tile into the other buffer, then single barrier
            if (kt < ktmax) {
                u16* d1 = &Ks[cur ^ 1][krow * 140 + kq];
                for (int i = 0; i < 4; i++) *(u16x8*)(d1 + i * 8) = kreg[i];
                u16* d2 = &Vt[cur ^ 1][vhd * 90 + vh2];
                for (int i = 0; i < 4; i++) *(u16x8*)(d2 + i * 8) = vreg[i];
            }
            __syncthreads();
        }

        // epilogue: out = O / sums ; ctx[pos*2 + b'][ nh'*128 + hd ]
        for (int reg = 0; reg < 16; reg++) {
            int row = (reg & 3) + 8 * (reg >> 2) + 4 * lh;
            float inv = 1.0f / sums[reg];
            int qg = q0w + row;
            int crow = qg * 2 + (bn >> 4);
            u16* cp = ctx + (size_t)crow * 2048 + (bn & 15) * 128 + ln;
            for (int ht = 0; ht < 4; ht++)
                cp[ht * 32] = f2b(o[ht][reg] * inv);
        }
    }
}

// ---------------------------------------------------------------------------
// launch
// ---------------------------------------------------------------------------
extern "C" void kernel_launch(void* const* d_in, const int* in_sizes, int n_in,
                              void* d_out, int out_size, void* d_ws, size_t ws_size,
                              hipStream_t stream)
{
    const float* hs    = (const float*)d_in[0];   // [2,2048,2048]
    const float* alibi = (const float*)d_in[1];   // [16,1,2048]
    const float* wqkv  = (const float*)d_in[2];   // [6144,2048]
    const float* bqkv  = (const float*)d_in[3];   // [6144]
    const float* wd    = (const float*)d_in[4];   // [2048,2048]
    const float* bd    = (const float*)d_in[5];   // [2048]
    float* out = (float*)d_out;                   // [2,2048,2048] f32

    char* ws = (char*)d_ws;
    u16* wqkv_b = (u16*)(ws + 0);            // 25,165,824 B
    u16* hs_b   = (u16*)(ws + 25165824);     // 16,777,216 B
    u16* ctx    = (u16*)(ws + 41943040);     // 16,777,216 B (bf16 [4096][2048])
    u16* wd_b   = wqkv_b;                    // alias: wqkv dead after gemm1
    u16* qb     = (u16*)(ws + 92274688);     // [32][2048][128] bf16
    u16* kb     = (u16*)(ws + 109051904);
    u16* vb     = (u16*)(ws + 125829120);    // end = 142,606,336 B

    cvt_f32_bf16<<<8192,  256, 0, stream>>>(hs,   hs_b,   2097152);
    cvt_wqkv   <<<12288, 256, 0, stream>>>(wqkv, wqkv_b, 3145728);

    // QKV GEMM with fused scatter/transpose epilogue (M=4096, N=6144, K=2048)
    gemm_bt<<<dim3(48, 32), 256, 0, stream>>>(hs_b, wqkv_b, bqkv, nullptr,
                                              qb, kb, vb, 4096, 6144, 2048, 0);

    cvt_f32_bf16<<<4096, 256, 0, stream>>>(wd, wd_b, 1048576);

    // 32x32-MFMA flash attention: 8 diag-pairs x 32 bn = 256 blocks, 1/CU
    attn<<<dim3(8, 32), 256, 0, stream>>>(qb, kb, vb, alibi, ctx);

    // out = ctx @ wd^T + bd, rows remapped to [b][s][h]   (M=4096, N=2048, K=2048)
    gemm_bt<<<dim3(16, 32), 256, 0, stream>>>(ctx, wd_b, bd, out,
                                              nullptr, nullptr, nullptr, 4096, 2048, 2048, 1);
}

// Round 7
// 463.830 us; speedup vs baseline: 1.0780x; 1.0780x over previous
//
#include <hip/hip_runtime.h>

typedef unsigned short u16;
typedef __bf16  bf16x8 __attribute__((ext_vector_type(8)));
typedef float   f32x4  __attribute__((ext_vector_type(4)));
typedef u16     u16x8  __attribute__((ext_vector_type(8)));
typedef u16     u16x4  __attribute__((ext_vector_type(4)));

#define QSCALE 0.12751744545f   // log2(e)/sqrt(128)

// ---------------------------------------------------------------------------
// helpers
// ---------------------------------------------------------------------------
__device__ __forceinline__ u16 f2b(float f) {               // f32 -> bf16 (RNE)
    unsigned u = __float_as_uint(f);
    unsigned r = u + 0x7FFFu + ((u >> 16) & 1u);
    return (u16)(r >> 16);
}
__device__ __forceinline__ float b2f(u16 b) {
    return __uint_as_float(((unsigned)b) << 16);
}
__device__ __forceinline__ void async16(const u16* g, u16* l) {
    // lane L's 16B land at (wave-uniform l) + L*16
    __builtin_amdgcn_global_load_lds(
        (__attribute__((address_space(1))) void*)(u16*)g,
        (__attribute__((address_space(3))) void*)l, 16, 0, 0);
}

// ---------------------------------------------------------------------------
// fp32 -> bf16 convert (float4 per thread)
// ---------------------------------------------------------------------------
__global__ void cvt_f32_bf16(const float* __restrict__ in, u16* __restrict__ out, int n4) {
    int i = blockIdx.x * blockDim.x + threadIdx.x;
    if (i >= n4) return;
    float4 f = ((const float4*)in)[i];
    u16x4 o;
    o[0] = f2b(f.x); o[1] = f2b(f.y); o[2] = f2b(f.z); o[3] = f2b(f.w);
    *(u16x4*)(out + (size_t)i * 4) = o;
}

// wqkv convert with q-row pre-scale folded in (rows with (row%384)<128 are q)
__global__ void cvt_wqkv(const float* __restrict__ in, u16* __restrict__ out, int n4) {
    int i = blockIdx.x * blockDim.x + threadIdx.x;
    if (i >= n4) return;
    int row = i >> 9;                       // 512 float4 per 2048-elem row
    float s = ((row % 384) < 128) ? QSCALE : 1.0f;
    float4 f = ((const float4*)in)[i];
    u16x4 o;
    o[0] = f2b(f.x * s); o[1] = f2b(f.y * s); o[2] = f2b(f.z * s); o[3] = f2b(f.w * s);
    *(u16x4*)(out + (size_t)i * 4) = o;
}

// ---------------------------------------------------------------------------
// bf16 NT GEMM: C = A[M,K] * B[N,K]^T + bias   (128x128 tile, BK=64, 2 panels)
// mode 0 (QKV fused): blockIdx.x = nh*3+part; writes qb/kb [bn][pos][hd]
//        directly (scrambled coords), v transposed through LDS to vb[bn][hd][pos]
// mode 1: store f32 with row remap orow = (row&1)*2048 + (row>>1)  (final out)
// ---------------------------------------------------------------------------
__global__ __launch_bounds__(256) void gemm_bt(
    const u16* __restrict__ A, const u16* __restrict__ B,
    const float* __restrict__ bias, void* __restrict__ C,
    u16* __restrict__ qb, u16* __restrict__ kb, u16* __restrict__ vb,
    int M, int N, int K, int mode)
{
    __shared__ u16 smem[16384];          // 32 KB: As | Bs, reused as v-transpose buf
    u16* As = smem;                      // [p][row][32k] : p*4096 + row*32 + kk
    u16* Bs = smem + 8192;

    int tid = threadIdx.x, wave = tid >> 6, lane = tid & 63;
    int lg = lane >> 4, lm = lane & 15;
    int wm = (wave & 1) * 64, wn = (wave >> 1) * 64;

    const u16* Ab = A + (size_t)(blockIdx.y * 128) * K;
    const u16* Bb = B + (size_t)(blockIdx.x * 128) * K;

    f32x4 acc[4][4];
    for (int i = 0; i < 4; i++)
        for (int j = 0; j < 4; j++)
            acc[i][j] = (f32x4){0.f, 0.f, 0.f, 0.f};

    int srow = (lane >> 2), skq = (lane & 3) * 8;   // lane -> row/k within 1KB chunk

    for (int k0 = 0; k0 < K; k0 += 64) {
        __syncthreads();
        for (int cc = wave; cc < 16; cc += 4) {
            int p = cc >> 3, c = cc & 7;
            int row = c * 16 + srow;
            size_t off = (size_t)row * K + k0 + p * 32 + skq;
            async16(Ab + off, &As[p * 4096 + c * 512]);
            async16(Bb + off, &Bs[p * 4096 + c * 512]);
        }
        __syncthreads();   // compiler drains vmcnt before barrier

        for (int p = 0; p < 2; p++) {
            bf16x8 af[4], bf[4];
            for (int i = 0; i < 4; i++) af[i] = *(const bf16x8*)&As[p * 4096 + (wm + i * 16 + lm) * 32 + lg * 8];
            for (int j = 0; j < 4; j++) bf[j] = *(const bf16x8*)&Bs[p * 4096 + (wn + j * 16 + lm) * 32 + lg * 8];
            for (int i = 0; i < 4; i++)
                for (int j = 0; j < 4; j++)
                    acc[i][j] = __builtin_amdgcn_mfma_f32_16x16x32_bf16(af[i], bf[j], acc[i][j], 0, 0, 0);
        }
    }

    if (mode == 1) {   // final output: f32, row remap
        for (int j = 0; j < 4; j++) {
            int col = blockIdx.x * 128 + wn + j * 16 + lm;
            float bv = bias[col];
            for (int i = 0; i < 4; i++) {
                int row0 = blockIdx.y * 128 + wm + i * 16 + lg * 4;
                for (int r = 0; r < 4; r++) {
                    int row = row0 + r;
                    int orow = ((row & 1) << 11) + (row >> 1);
                    ((float*)C)[(size_t)orow * N + col] = acc[i][j][r] + bv;
                }
            }
        }
        return;
    }

    // ---- mode 0: fused QKV scatter epilogue ----
    int ct = blockIdx.x;
    int nh = ct / 3, part = ct - nh * 3;
    float bscale = (part == 0) ? QSCALE : 1.0f;
    int rbase = blockIdx.y * 128;                 // global row base (= b*2048 + s0)
    int b = rbase >> 11;
    int s0 = rbase & 2047;

    if (part < 2) {   // q or k -> [bn][pos][hd], scalar u16 stores (32B runs)
        u16* dst0 = part ? kb : qb;
        for (int j = 0; j < 4; j++) {
            int hd = wn + j * 16 + lm;
            float bv = bias[ct * 128 + hd] * bscale;
            for (int i = 0; i < 4; i++) {
                for (int r = 0; r < 4; r++) {
                    int rl = wm + i * 16 + lg * 4 + r;       // local row 0..127
                    int s = s0 + rl;
                    int bn = (s & 1) * 16 + nh;
                    int pos = (b << 10) + (s >> 1);
                    dst0[((size_t)(bn * 2048 + pos)) * 128 + hd] = f2b(acc[i][j][r] + bv);
                }
            }
        }
    } else {          // v -> transpose via LDS -> vb[bn][hd][pos] (128B runs)
        u16 (*arr)[64][128] = (u16(*)[64][128])smem;   // [par][pos_local][hd]
        __syncthreads();   // all waves done reading As/Bs
        for (int j = 0; j < 4; j++) {
            int hd = wn + j * 16 + lm;
            float bv = bias[ct * 128 + hd];
            for (int i = 0; i < 4; i++) {
                for (int r = 0; r < 4; r++) {
                    int rl = wm + i * 16 + lg * 4 + r;
                    arr[rl & 1][rl >> 1][hd] = f2b(acc[i][j][r] + bv);
                }
            }
        }
        __syncthreads();
        int hd = tid & 127, par = tid >> 7;
        int bn = par * 16 + nh;
        int pos0 = (b << 10) + (s0 >> 1);
        u16* dst = vb + ((size_t)(bn * 128 + hd)) * 2048 + pos0;
        for (int c = 0; c < 8; c++) {
            u16x8 w;
            for (int e = 0; e < 8; e++) w[e] = arr[par][c * 8 + e][hd];
            *(u16x8*)(dst + c * 8) = w;
        }
    }
}

// ---------------------------------------------------------------------------
// flash attention, scrambled (bn,pos) space — split-K uniform-load edition.
// 16x16x32 MFMA, 32 q-rows/wave, 128-row Q-tile/block, K-tiles of 64 staged
// in single-buffered LDS (60 KB -> 2 blocks/CU = 8 waves/CU for latency
// hiding). No-max softmax is ADDITIVE, so each qt's k-range splits into two
// halves on different blocks; deterministic pairing gives every block exactly
// 17 iterations (perfect balance at grid 512 = 2 blocks/CU, no backfill
// needed). Partials -> Opart[2][32][2048][128] f32 (single writer, no
// atomics); finalize kernel sums + normalizes into ctx.
//   j = blockIdx.x (0..15), bn = blockIdx.y:
//   j<8 : part0: (qt=15-j, kt 0..15-j)[16-j] + (qt=j, kt 0..j)[j+1]    = 17
//   j>=8: part1: (qt=j, kt j+1..2j+1)[j+1] + (qt=15-j, kt 16-j..31-2j)[16-j]
// ---------------------------------------------------------------------------
__global__ __launch_bounds__(256, 2) void attn(
    const u16* __restrict__ qb, const u16* __restrict__ kb,
    const u16* __restrict__ vb, const float* __restrict__ alibi,
    float* __restrict__ Opart, float* __restrict__ Spart)
{
    __shared__ u16 Ks[64 * 140];    // K tile [kpos][hd], stride 140 (frag reads conflict-free)
    __shared__ u16 Vt[128 * 90];    // V^T tile [hd][kpos], stride 90
    __shared__ u16 Ps[4][32 * 76];  // per-wave P [q32][k64], stride 76 (write groups disjoint)

    int j = blockIdx.x, bn = blockIdx.y;
    int tid = threadIdx.x, wave = tid >> 6, lane = tid & 63;
    int lg = lane >> 4, lm = lane & 15;

    const float* al = alibi + (bn & 15) * 2048;

    int krow = tid >> 2, kq = (tid & 3) * 32;
    int vhd  = tid >> 1, vh2 = (tid & 1) * 32;
    const u16* ksrc0 = kb + (size_t)(bn * 2048 + krow) * 128 + kq;
    const u16* vsrc0 = vb + (size_t)(bn * 128 + vhd) * 2048 + vh2;

    u16* ps = &Ps[wave][0];
    bf16x8 ones;
    {
        u16x8 t;
        for (int e = 0; e < 8; e++) t[e] = 0x3F80;   // bf16 1.0
        ones = *(bf16x8*)&t;
    }

    int part, qts[2], kA[2], kB[2];
    if (j < 8) {
        part = 0;
        qts[0] = 15 - j; kA[0] = 0;      kB[0] = 15 - j;
        qts[1] = j;      kA[1] = 0;      kB[1] = j;
    } else {
        part = 1;
        qts[0] = j;      kA[0] = j + 1;  kB[0] = 2 * j + 1;
        qts[1] = 15 - j; kA[1] = 16 - j; kB[1] = 31 - 2 * j;
    }

    for (int s = 0; s < 2; s++) {
        int qt = qts[s], ktA = kA[s], ktB = kB[s];
        int q0w = qt * 128 + wave * 32;      // wave's first q row (32 rows, 2 MFMA row-tiles)

        bf16x8 qf[2][4];
        for (int i = 0; i < 2; i++) {
            const u16* qp = qb + ((size_t)bn * 2048 + q0w + i * 16 + lm) * 128 + lg * 8;
            for (int kc = 0; kc < 4; kc++) qf[i][kc] = *(const bf16x8*)(qp + kc * 32);
        }

        f32x4 o[2][8], sums[2];
        for (int i = 0; i < 2; i++) {
            sums[i] = (f32x4){0.f, 0.f, 0.f, 0.f};
            for (int h = 0; h < 8; h++) o[i][h] = (f32x4){0.f, 0.f, 0.f, 0.f};
        }

        // register prefetch of first tile
        u16x8 kreg[4], vreg[4];
        {
            const u16* s1 = ksrc0 + (size_t)ktA * 64 * 128;
            const u16* s2 = vsrc0 + ktA * 64;
            for (int i = 0; i < 4; i++) kreg[i] = *(const u16x8*)(s1 + i * 8);
            for (int i = 0; i < 4; i++) vreg[i] = *(const u16x8*)(s2 + i * 8);
        }

        for (int kt = ktA; kt <= ktB; kt++) {
            int k0 = kt * 64;
            __syncthreads();   // previous tile fully consumed
            {
                u16* d1 = &Ks[krow * 140 + kq];
                for (int i = 0; i < 4; i++) *(u16x8*)(d1 + i * 8) = kreg[i];
                u16* d2 = &Vt[vhd * 90 + vh2];
                for (int i = 0; i < 4; i++) *(u16x8*)(d2 + i * 8) = vreg[i];
            }
            __syncthreads();

            if (kt < ktB) {   // prefetch next tile; lands behind MFMA
                const u16* s1 = ksrc0 + (size_t)(kt + 1) * 64 * 128;
                const u16* s2 = vsrc0 + (kt + 1) * 64;
                for (int i = 0; i < 4; i++) kreg[i] = *(const u16x8*)(s1 + i * 8);
                for (int i = 0; i < 4; i++) vreg[i] = *(const u16x8*)(s2 + i * 8);
            }

            // S = Q K^T : 32 q-rows x 64 k-cols; K B-frags shared across both row-tiles
            bool domask = (k0 + 63 > q0w);
            for (int tc = 0; tc < 4; tc++) {
                const u16* kr = &Ks[(tc * 16 + lm) * 140 + lg * 8];
                f32x4 a0 = (f32x4){0.f, 0.f, 0.f, 0.f};
                f32x4 a1 = (f32x4){0.f, 0.f, 0.f, 0.f};
                for (int kc = 0; kc < 4; kc++) {
                    bf16x8 bfr = *(const bf16x8*)(kr + kc * 32);
                    a0 = __builtin_amdgcn_mfma_f32_16x16x32_bf16(qf[0][kc], bfr, a0, 0, 0, 0);
                    a1 = __builtin_amdgcn_mfma_f32_16x16x32_bf16(qf[1][kc], bfr, a1, 0, 0, 0);
                }
                int kg = k0 + tc * 16 + lm;
                float av = (al[kg] - 8.0f) * 1.4426950408889634f;
                for (int r = 0; r < 4; r++) {
                    float v0 = a0[r] + av, v1 = a1[r] + av;
                    if (domask) {
                        int r0 = q0w + lg * 4 + r;
                        if (kg > r0) v0 = -3e38f;
                        if (kg > r0 + 16) v1 = -3e38f;
                    }
                    ps[(lg * 4 + r) * 76 + tc * 16 + lm]        = f2b(__builtin_amdgcn_exp2f(v0));
                    ps[(16 + lg * 4 + r) * 76 + tc * 16 + lm]   = f2b(__builtin_amdgcn_exp2f(v1));
                }
            }

            // O += P V ; sums += P * ones  (V B-frags shared across both row-tiles)
            for (int kc = 0; kc < 2; kc++) {
                bf16x8 pf0 = *(const bf16x8*)&ps[lm * 76 + kc * 32 + lg * 8];
                bf16x8 pf1 = *(const bf16x8*)&ps[(16 + lm) * 76 + kc * 32 + lg * 8];
                for (int ht = 0; ht < 8; ht++) {
                    bf16x8 vf = *(const bf16x8*)&Vt[(ht * 16 + lm) * 90 + kc * 32 + lg * 8];
                    o[0][ht] = __builtin_amdgcn_mfma_f32_16x16x32_bf16(pf0, vf, o[0][ht], 0, 0, 0);
                    o[1][ht] = __builtin_amdgcn_mfma_f32_16x16x32_bf16(pf1, vf, o[1][ht], 0, 0, 0);
                }
                sums[0] = __builtin_amdgcn_mfma_f32_16x16x32_bf16(pf0, ones, sums[0], 0, 0, 0);
                sums[1] = __builtin_amdgcn_mfma_f32_16x16x32_bf16(pf1, ones, sums[1], 0, 0, 0);
            }
        }

        // flush partials (single writer per (part,qt,bn) -> plain stores)
        float* Op = Opart + (((size_t)part * 32 + bn) * 2048 + qt * 128) * 128;
        for (int i = 0; i < 2; i++)
            for (int r = 0; r < 4; r++) {
                int row = wave * 32 + i * 16 + lg * 4 + r;
                float* orow = Op + (size_t)row * 128 + lm;
                for (int ht = 0; ht < 8; ht++) orow[ht * 16] = o[i][ht][r];
            }
        if (lm == 0) {   // every lane of a 16-group holds the same row-sum
            float* Sp = Spart + ((size_t)part * 32 + bn) * 2048 + qt * 128 + wave * 32;
            for (int i = 0; i < 2; i++)
                for (int r = 0; r < 4; r++)
                    Sp[i * 16 + lg * 4 + r] = sums[i][r];
        }
    }
}

// ---------------------------------------------------------------------------
// finalize: ctx = f2b((Opart[0]+Opart[1]) / (Spart[0]+Spart[1]))
// ctx layout [pos*2 + bn>>4][(bn&15)*128 + hd]
// ---------------------------------------------------------------------------
__global__ void attn_fin(const float* __restrict__ Opart, const float* __restrict__ Spart,
                         u16* __restrict__ ctx)
{
    int idx = blockIdx.x * 256 + threadIdx.x;   // 32*2048*16
    int hd8 = idx & 15;
    int q   = (idx >> 4) & 2047;
    int bn  = idx >> 15;
    size_t o0 = (((size_t)bn) * 2048 + q) * 128 + hd8 * 8;
    size_t o1 = (size_t)32 * 2048 * 128 + o0;
    float s = Spart[bn * 2048 + q] + Spart[32 * 2048 + bn * 2048 + q];
    float inv = 1.0f / s;
    const float4* A = (const float4*)(Opart + o0);
    const float4* B = (const float4*)(Opart + o1);
    float4 a0 = A[0], a1 = A[1], b0 = B[0], b1 = B[1];
    u16x8 w;
    w[0] = f2b((a0.x + b0.x) * inv); w[1] = f2b((a0.y + b0.y) * inv);
    w[2] = f2b((a0.z + b0.z) * inv); w[3] = f2b((a0.w + b0.w) * inv);
    w[4] = f2b((a1.x + b1.x) * inv); w[5] = f2b((a1.y + b1.y) * inv);
    w[6] = f2b((a1.z + b1.z) * inv); w[7] = f2b((a1.w + b1.w) * inv);
    *(u16x8*)(ctx + ((size_t)(q * 2 + (bn >> 4))) * 2048 + (bn & 15) * 128 + hd8 * 8) = w;
}

// ---------------------------------------------------------------------------
// launch
// ---------------------------------------------------------------------------
extern "C" void kernel_launch(void* const* d_in, const int* in_sizes, int n_in,
                              void* d_out, int out_size, void* d_ws, size_t ws_size,
                              hipStream_t stream)
{
    const float* hs    = (const float*)d_in[0];   // [2,2048,2048]
    const float* alibi = (const float*)d_in[1];   // [16,1,2048]
    const float* wqkv  = (const float*)d_in[2];   // [6144,2048]
    const float* bqkv  = (const float*)d_in[3];   // [6144]
    const float* wd    = (const float*)d_in[4];   // [2048,2048]
    const float* bd    = (const float*)d_in[5];   // [2048]
    float* out = (float*)d_out;                   // [2,2048,2048] f32

    char* ws = (char*)d_ws;
    // phase 1 (gemm1 inputs, dead afterwards):
    u16*   wqkv_b = (u16*)(ws + 0);           // 25,165,824 B
    u16*   hs_b   = (u16*)(ws + 25165824);    // 16,777,216 B
    // phase 2 (attn partials overlay the dead gemm1 inputs):
    float* Opart  = (float*)(ws + 0);         // [2][32][2048][128] f32 = 67,108,864 B
    u16*   ctx    = (u16*)(ws + 67108864);    // 16,777,216 B (bf16 [4096][2048])
    u16*   wd_b   = (u16*)(ws + 83886080);    // 8,388,608 B, ends 92,274,688
    u16*   qb     = (u16*)(ws + 92274688);    // [32][2048][128] bf16
    u16*   kb     = (u16*)(ws + 109051904);
    u16*   vb     = (u16*)(ws + 125829120);   // end = 142,606,336 B
    float* Spart  = (float*)d_out;            // 524,288 B scratch; gemm2 overwrites all of d_out

    cvt_f32_bf16<<<8192,  256, 0, stream>>>(hs,   hs_b,   2097152);
    cvt_wqkv   <<<12288, 256, 0, stream>>>(wqkv, wqkv_b, 3145728);

    // QKV GEMM with fused scatter/transpose epilogue (M=4096, N=6144, K=2048)
    gemm_bt<<<dim3(48, 32), 256, 0, stream>>>(hs_b, wqkv_b, bqkv, nullptr,
                                              qb, kb, vb, 4096, 6144, 2048, 0);

    cvt_f32_bf16<<<4096, 256, 0, stream>>>(wd, wd_b, 1048576);

    // split-K flash attention: 16 x 32 = 512 uniform blocks (17 iters each), 2/CU
    attn<<<dim3(16, 32), 256, 0, stream>>>(qb, kb, vb, alibi, Opart, Spart);
    attn_fin<<<4096, 256, 0, stream>>>(Opart, Spart, ctx);

    // out = ctx @ wd^T + bd, rows remapped to [b][s][h]   (M=4096, N=2048, K=2048)
    gemm_bt<<<dim3(16, 32), 256, 0, stream>>>(ctx, wd_b, bd, out,
                                              nullptr, nullptr, nullptr, 4096, 2048, 2048, 1);
}

// Round 8
// 401.998 us; speedup vs baseline: 1.2438x; 1.1538x over previous
//
#include <hip/hip_runtime.h>

typedef unsigned short u16;
typedef __bf16  bf16x8 __attribute__((ext_vector_type(8)));
typedef float   f32x4  __attribute__((ext_vector_type(4)));
typedef u16     u16x8  __attribute__((ext_vector_type(8)));
typedef u16     u16x4  __attribute__((ext_vector_type(4)));

#define QSCALE 0.12751744545f   // log2(e)/sqrt(128)

// ---------------------------------------------------------------------------
// helpers
// ---------------------------------------------------------------------------
__device__ __forceinline__ u16 f2b(float f) {               // f32 -> bf16 (RNE)
    unsigned u = __float_as_uint(f);
    unsigned r = u + 0x7FFFu + ((u >> 16) & 1u);
    return (u16)(r >> 16);
}
__device__ __forceinline__ float b2f(u16 b) {
    return __uint_as_float(((unsigned)b) << 16);
}
__device__ __forceinline__ void async16(const u16* g, u16* l) {
    // lane L's 16B land at (wave-uniform l) + L*16
    __builtin_amdgcn_global_load_lds(
        (__attribute__((address_space(1))) void*)(u16*)g,
        (__attribute__((address_space(3))) void*)l, 16, 0, 0);
}

// ---------------------------------------------------------------------------
// fp32 -> bf16 convert (float4 per thread)
// ---------------------------------------------------------------------------
__global__ void cvt_f32_bf16(const float* __restrict__ in, u16* __restrict__ out, int n4) {
    int i = blockIdx.x * blockDim.x + threadIdx.x;
    if (i >= n4) return;
    float4 f = ((const float4*)in)[i];
    u16x4 o;
    o[0] = f2b(f.x); o[1] = f2b(f.y); o[2] = f2b(f.z); o[3] = f2b(f.w);
    *(u16x4*)(out + (size_t)i * 4) = o;
}

// wqkv convert with q-row pre-scale folded in (rows with (row%384)<128 are q)
__global__ void cvt_wqkv(const float* __restrict__ in, u16* __restrict__ out, int n4) {
    int i = blockIdx.x * blockDim.x + threadIdx.x;
    if (i >= n4) return;
    int row = i >> 9;                       // 512 float4 per 2048-elem row
    float s = ((row % 384) < 128) ? QSCALE : 1.0f;
    float4 f = ((const float4*)in)[i];
    u16x4 o;
    o[0] = f2b(f.x * s); o[1] = f2b(f.y * s); o[2] = f2b(f.z * s); o[3] = f2b(f.w * s);
    *(u16x4*)(out + (size_t)i * 4) = o;
}

// ---------------------------------------------------------------------------
// bf16 NT GEMM: C = A[M,K] * B[N,K]^T + bias   (128x128 tile, BK=64, 2 panels)
// mode 0 (QKV fused): blockIdx.x = nh*3+part; writes qb/kb [bn][pos][hd]
//        directly (scrambled coords), v transposed through LDS to vb[bn][hd][pos]
// mode 1: store f32 with row remap orow = (row&1)*2048 + (row>>1)  (final out)
// ---------------------------------------------------------------------------
__global__ __launch_bounds__(256) void gemm_bt(
    const u16* __restrict__ A, const u16* __restrict__ B,
    const float* __restrict__ bias, void* __restrict__ C,
    u16* __restrict__ qb, u16* __restrict__ kb, u16* __restrict__ vb,
    int M, int N, int K, int mode)
{
    __shared__ u16 smem[16384];          // 32 KB: As | Bs, reused as v-transpose buf
    u16* As = smem;                      // [p][row][32k] : p*4096 + row*32 + kk
    u16* Bs = smem + 8192;

    int tid = threadIdx.x, wave = tid >> 6, lane = tid & 63;
    int lg = lane >> 4, lm = lane & 15;
    int wm = (wave & 1) * 64, wn = (wave >> 1) * 64;

    const u16* Ab = A + (size_t)(blockIdx.y * 128) * K;
    const u16* Bb = B + (size_t)(blockIdx.x * 128) * K;

    f32x4 acc[4][4];
    for (int i = 0; i < 4; i++)
        for (int j = 0; j < 4; j++)
            acc[i][j] = (f32x4){0.f, 0.f, 0.f, 0.f};

    int srow = (lane >> 2), skq = (lane & 3) * 8;   // lane -> row/k within 1KB chunk

    for (int k0 = 0; k0 < K; k0 += 64) {
        __syncthreads();
        for (int cc = wave; cc < 16; cc += 4) {
            int p = cc >> 3, c = cc & 7;
            int row = c * 16 + srow;
            size_t off = (size_t)row * K + k0 + p * 32 + skq;
            async16(Ab + off, &As[p * 4096 + c * 512]);
            async16(Bb + off, &Bs[p * 4096 + c * 512]);
        }
        __syncthreads();   // compiler drains vmcnt before barrier

        for (int p = 0; p < 2; p++) {
            bf16x8 af[4], bf[4];
            for (int i = 0; i < 4; i++) af[i] = *(const bf16x8*)&As[p * 4096 + (wm + i * 16 + lm) * 32 + lg * 8];
            for (int j = 0; j < 4; j++) bf[j] = *(const bf16x8*)&Bs[p * 4096 + (wn + j * 16 + lm) * 32 + lg * 8];
            for (int i = 0; i < 4; i++)
                for (int j = 0; j < 4; j++)
                    acc[i][j] = __builtin_amdgcn_mfma_f32_16x16x32_bf16(af[i], bf[j], acc[i][j], 0, 0, 0);
        }
    }

    if (mode == 1) {   // final output: f32, row remap
        for (int j = 0; j < 4; j++) {
            int col = blockIdx.x * 128 + wn + j * 16 + lm;
            float bv = bias[col];
            for (int i = 0; i < 4; i++) {
                int row0 = blockIdx.y * 128 + wm + i * 16 + lg * 4;
                for (int r = 0; r < 4; r++) {
                    int row = row0 + r;
                    int orow = ((row & 1) << 11) + (row >> 1);
                    ((float*)C)[(size_t)orow * N + col] = acc[i][j][r] + bv;
                }
            }
        }
        return;
    }

    // ---- mode 0: fused QKV scatter epilogue ----
    int ct = blockIdx.x;
    int nh = ct / 3, part = ct - nh * 3;
    float bscale = (part == 0) ? QSCALE : 1.0f;
    int rbase = blockIdx.y * 128;                 // global row base (= b*2048 + s0)
    int b = rbase >> 11;
    int s0 = rbase & 2047;

    if (part < 2) {   // q or k -> [bn][pos][hd], scalar u16 stores (32B runs)
        u16* dst0 = part ? kb : qb;
        for (int j = 0; j < 4; j++) {
            int hd = wn + j * 16 + lm;
            float bv = bias[ct * 128 + hd] * bscale;
            for (int i = 0; i < 4; i++) {
                for (int r = 0; r < 4; r++) {
                    int rl = wm + i * 16 + lg * 4 + r;       // local row 0..127
                    int s = s0 + rl;
                    int bn = (s & 1) * 16 + nh;
                    int pos = (b << 10) + (s >> 1);
                    dst0[((size_t)(bn * 2048 + pos)) * 128 + hd] = f2b(acc[i][j][r] + bv);
                }
            }
        }
    } else {          // v -> transpose via LDS -> vb[bn][hd][pos] (128B runs)
        u16 (*arr)[64][128] = (u16(*)[64][128])smem;   // [par][pos_local][hd]
        __syncthreads();   // all waves done reading As/Bs
        for (int j = 0; j < 4; j++) {
            int hd = wn + j * 16 + lm;
            float bv = bias[ct * 128 + hd];
            for (int i = 0; i < 4; i++) {
                for (int r = 0; r < 4; r++) {
                    int rl = wm + i * 16 + lg * 4 + r;
                    arr[rl & 1][rl >> 1][hd] = f2b(acc[i][j][r] + bv);
                }
            }
        }
        __syncthreads();
        int hd = tid & 127, par = tid >> 7;
        int bn = par * 16 + nh;
        int pos0 = (b << 10) + (s0 >> 1);
        u16* dst = vb + ((size_t)(bn * 128 + hd)) * 2048 + pos0;
        for (int c = 0; c < 8; c++) {
            u16x8 w;
            for (int e = 0; e < 8; e++) w[e] = arr[par][c * 8 + e][hd];
            *(u16x8*)(dst + c * 8) = w;
        }
    }
}

// ---------------------------------------------------------------------------
// flash attention, scrambled (bn,pos) space — sector-perfect staging edition.
// Same split-K balance as round 7 (512 uniform blocks, 17 iters each, 2/CU),
// but K/V tiles staged via global_load_lds width-16 with per-instruction-
// contiguous 1KB chunks (4 lanes = one full 64B sector; no request
// amplification) into chunked unpadded LDS:
//   Ks[kc 0..3][row 0..63][32]   (kc = hd/32 chunk)  -- wave w stages kc=w
//   Vt[ch 0..1][hd 0..127][32]   (ch = kpos/32 chunk)
// Fragment reads have the same free ~2-way bank pattern as the m97 GEMM.
// No-max softmax (shift 8 in alibi, log2e in q), row sums via ones-MFMA.
// Partials bf16 -> Opart[2][32][2048][128]; finalize merges into ctx.
// ---------------------------------------------------------------------------
__global__ __launch_bounds__(256, 2) void attn(
    const u16* __restrict__ qb, const u16* __restrict__ kb,
    const u16* __restrict__ vb, const float* __restrict__ alibi,
    u16* __restrict__ Opart, float* __restrict__ Spart)
{
    __shared__ u16 Ks[4 * 2048];    // [kc][row][32]
    __shared__ u16 Vt[2 * 4096];    // [ch][hd][32]
    __shared__ u16 Ps[4][32 * 76];  // per-wave P [q32][k64], stride 76

    int j = blockIdx.x, bn = blockIdx.y;
    int tid = threadIdx.x, wave = tid >> 6, lane = tid & 63;
    int lg = lane >> 4, lm = lane & 15;

    const float* al = alibi + (bn & 15) * 2048;

    // per-lane global staging bases (sector-contiguous per instruction)
    // K chunk i (rows i*16..+15, hd cols wave*32..+31):
    //   lane L -> row += L>>2, col += (L&3)*8
    const u16* kK = kb + ((size_t)bn * 2048 + (lane >> 2)) * 128 + wave * 32 + (lane & 3) * 8;
    // V chunk i (hd rows (wave&1)*64 + i*16..+15, k cols (wave>>1)*32..+31):
    const u16* kV = vb + ((size_t)(bn * 128 + (wave & 1) * 64 + (lane >> 2))) * 2048
                       + (wave >> 1) * 32 + (lane & 3) * 8;
    // wave-uniform LDS dests
    u16* KsW = Ks + wave * 2048;                               // + i*512
    u16* VtW = Vt + (wave >> 1) * 4096 + (wave & 1) * 2048;    // + i*512

    u16* ps = &Ps[wave][0];
    bf16x8 ones;
    {
        u16x8 t;
        for (int e = 0; e < 8; e++) t[e] = 0x3F80;   // bf16 1.0
        ones = *(bf16x8*)&t;
    }

    int part, qts[2], kA[2], kB[2];
    if (j < 8) {
        part = 0;
        qts[0] = 15 - j; kA[0] = 0;      kB[0] = 15 - j;
        qts[1] = j;      kA[1] = 0;      kB[1] = j;
    } else {
        part = 1;
        qts[0] = j;      kA[0] = j + 1;  kB[0] = 2 * j + 1;
        qts[1] = 15 - j; kA[1] = 16 - j; kB[1] = 31 - 2 * j;
    }

    for (int s = 0; s < 2; s++) {
        int qt = qts[s], ktA = kA[s], ktB = kB[s];
        int q0w = qt * 128 + wave * 32;      // wave's first q row (2 MFMA row-tiles)

        bf16x8 qf[2][4];
        for (int i = 0; i < 2; i++) {
            const u16* qp = qb + ((size_t)bn * 2048 + q0w + i * 16 + lm) * 128 + lg * 8;
            for (int kc = 0; kc < 4; kc++) qf[i][kc] = *(const bf16x8*)(qp + kc * 32);
        }

        f32x4 o[2][8], sums[2];
        for (int i = 0; i < 2; i++) {
            sums[i] = (f32x4){0.f, 0.f, 0.f, 0.f};
            for (int h = 0; h < 8; h++) o[i][h] = (f32x4){0.f, 0.f, 0.f, 0.f};
        }

        for (int kt = ktA; kt <= ktB; kt++) {
            int k0 = kt * 64;
            __syncthreads();   // previous tile fully consumed
            {
                const u16* kg = kK + (size_t)k0 * 128;
                const u16* vg = kV + k0;
                for (int i = 0; i < 4; i++) {
                    async16(kg + (size_t)i * 2048, KsW + i * 512);     // 16 rows x 256B
                    async16(vg + (size_t)i * 32768, VtW + i * 512);    // 16 hd-rows x 4KB apart
                }
            }
            __syncthreads();   // compiler drains vmcnt before barrier

            // S = Q K^T : 32 q-rows x 64 k-cols; K B-frags shared across row-tiles
            bool domask = (k0 + 63 > q0w);
            for (int tc = 0; tc < 4; tc++) {
                f32x4 a0 = (f32x4){0.f, 0.f, 0.f, 0.f};
                f32x4 a1 = (f32x4){0.f, 0.f, 0.f, 0.f};
                for (int kc = 0; kc < 4; kc++) {
                    bf16x8 bfr = *(const bf16x8*)&Ks[kc * 2048 + (tc * 16 + lm) * 32 + lg * 8];
                    a0 = __builtin_amdgcn_mfma_f32_16x16x32_bf16(qf[0][kc], bfr, a0, 0, 0, 0);
                    a1 = __builtin_amdgcn_mfma_f32_16x16x32_bf16(qf[1][kc], bfr, a1, 0, 0, 0);
                }
                int kg = k0 + tc * 16 + lm;
                float av = (al[kg] - 8.0f) * 1.4426950408889634f;
                for (int r = 0; r < 4; r++) {
                    float v0 = a0[r] + av, v1 = a1[r] + av;
                    if (domask) {
                        int r0 = q0w + lg * 4 + r;
                        if (kg > r0) v0 = -3e38f;
                        if (kg > r0 + 16) v1 = -3e38f;
                    }
                    ps[(lg * 4 + r) * 76 + tc * 16 + lm]      = f2b(__builtin_amdgcn_exp2f(v0));
                    ps[(16 + lg * 4 + r) * 76 + tc * 16 + lm] = f2b(__builtin_amdgcn_exp2f(v1));
                }
            }

            // O += P V ; sums += P * ones  (V B-frags shared across row-tiles)
            for (int kc = 0; kc < 2; kc++) {
                bf16x8 pf0 = *(const bf16x8*)&ps[lm * 76 + kc * 32 + lg * 8];
                bf16x8 pf1 = *(const bf16x8*)&ps[(16 + lm) * 76 + kc * 32 + lg * 8];
                for (int ht = 0; ht < 8; ht++) {
                    bf16x8 vf = *(const bf16x8*)&Vt[kc * 4096 + (ht * 16 + lm) * 32 + lg * 8];
                    o[0][ht] = __builtin_amdgcn_mfma_f32_16x16x32_bf16(pf0, vf, o[0][ht], 0, 0, 0);
                    o[1][ht] = __builtin_amdgcn_mfma_f32_16x16x32_bf16(pf1, vf, o[1][ht], 0, 0, 0);
                }
                sums[0] = __builtin_amdgcn_mfma_f32_16x16x32_bf16(pf0, ones, sums[0], 0, 0, 0);
                sums[1] = __builtin_amdgcn_mfma_f32_16x16x32_bf16(pf1, ones, sums[1], 0, 0, 0);
            }
        }

        // flush bf16 partials (single writer per (part,qt,bn) -> plain stores)
        u16* Op = Opart + (((size_t)part * 32 + bn) * 2048 + qt * 128) * 128;
        for (int i = 0; i < 2; i++)
            for (int r = 0; r < 4; r++) {
                int row = wave * 32 + i * 16 + lg * 4 + r;
                u16* orow = Op + (size_t)row * 128 + lm;
                for (int ht = 0; ht < 8; ht++) orow[ht * 16] = f2b(o[i][ht][r]);
            }
        if (lm == 0) {   // every lane of a 16-group holds the same row-sum
            float* Sp = Spart + ((size_t)part * 32 + bn) * 2048 + qt * 128 + wave * 32;
            for (int i = 0; i < 2; i++)
                for (int r = 0; r < 4; r++)
                    Sp[i * 16 + lg * 4 + r] = sums[i][r];
        }
    }
}

// ---------------------------------------------------------------------------
// finalize: ctx = f2b((Opart[0]+Opart[1]) / (Spart[0]+Spart[1]))
// ctx layout [pos*2 + bn>>4][(bn&15)*128 + hd]
// ---------------------------------------------------------------------------
__global__ void attn_fin(const u16* __restrict__ Opart, const float* __restrict__ Spart,
                         u16* __restrict__ ctx)
{
    int idx = blockIdx.x * 256 + threadIdx.x;   // 32*2048*16
    int hd8 = idx & 15;
    int q   = (idx >> 4) & 2047;
    int bn  = idx >> 15;
    size_t o0 = (((size_t)bn) * 2048 + q) * 128 + hd8 * 8;
    size_t o1 = o0 + (size_t)32 * 2048 * 128;
    float s = Spart[bn * 2048 + q] + Spart[32 * 2048 + bn * 2048 + q];
    float inv = 1.0f / s;
    u16x8 a = *(const u16x8*)(Opart + o0);
    u16x8 b = *(const u16x8*)(Opart + o1);
    u16x8 w;
    for (int e = 0; e < 8; e++) w[e] = f2b((b2f(a[e]) + b2f(b[e])) * inv);
    *(u16x8*)(ctx + ((size_t)(q * 2 + (bn >> 4))) * 2048 + (bn & 15) * 128 + hd8 * 8) = w;
}

// ---------------------------------------------------------------------------
// launch
// ---------------------------------------------------------------------------
extern "C" void kernel_launch(void* const* d_in, const int* in_sizes, int n_in,
                              void* d_out, int out_size, void* d_ws, size_t ws_size,
                              hipStream_t stream)
{
    const float* hs    = (const float*)d_in[0];   // [2,2048,2048]
    const float* alibi = (const float*)d_in[1];   // [16,1,2048]
    const float* wqkv  = (const float*)d_in[2];   // [6144,2048]
    const float* bqkv  = (const float*)d_in[3];   // [6144]
    const float* wd    = (const float*)d_in[4];   // [2048,2048]
    const float* bd    = (const float*)d_in[5];   // [2048]
    float* out = (float*)d_out;                   // [2,2048,2048] f32

    char* ws = (char*)d_ws;
    // phase 1 (gemm1 inputs, dead afterwards):
    u16*   wqkv_b = (u16*)(ws + 0);           // 25,165,824 B
    u16*   hs_b   = (u16*)(ws + 25165824);    // 16,777,216 B
    // phase 2 (attn partials overlay the dead gemm1 inputs):
    u16*   Opart  = (u16*)(ws + 0);           // [2][32][2048][128] bf16 = 33,554,432 B
    u16*   ctx    = (u16*)(ws + 67108864);    // 16,777,216 B (bf16 [4096][2048])
    u16*   wd_b   = (u16*)(ws + 83886080);    // 8,388,608 B, ends 92,274,688
    u16*   qb     = (u16*)(ws + 92274688);    // [32][2048][128] bf16
    u16*   kb     = (u16*)(ws + 109051904);
    u16*   vb     = (u16*)(ws + 125829120);   // end = 142,606,336 B
    float* Spart  = (float*)d_out;            // 524,288 B scratch; gemm2 overwrites all of d_out

    cvt_f32_bf16<<<8192,  256, 0, stream>>>(hs,   hs_b,   2097152);
    cvt_wqkv   <<<12288, 256, 0, stream>>>(wqkv, wqkv_b, 3145728);

    // QKV GEMM with fused scatter/transpose epilogue (M=4096, N=6144, K=2048)
    gemm_bt<<<dim3(48, 32), 256, 0, stream>>>(hs_b, wqkv_b, bqkv, nullptr,
                                              qb, kb, vb, 4096, 6144, 2048, 0);

    cvt_f32_bf16<<<4096, 256, 0, stream>>>(wd, wd_b, 1048576);

    // split-K flash attention: 16 x 32 = 512 uniform blocks (17 iters each), 2/CU
    attn<<<dim3(16, 32), 256, 0, stream>>>(qb, kb, vb, alibi, Opart, Spart);
    attn_fin<<<4096, 256, 0, stream>>>(Opart, Spart, ctx);

    // out = ctx @ wd^T + bd, rows remapped to [b][s][h]   (M=4096, N=2048, K=2048)
    gemm_bt<<<dim3(16, 32), 256, 0, stream>>>(ctx, wd_b, bd, out,
                                              nullptr, nullptr, nullptr, 4096, 2048, 2048, 1);
}